// Round 3
// baseline (1056.614 us; speedup 1.0000x reference)
//
#include <hip/hip_runtime.h>

typedef unsigned short u16;
typedef unsigned int   u32;
typedef __attribute__((ext_vector_type(8))) short s8v;   // 8 bf16 (as shorts) = 4 VGPRs
typedef __attribute__((ext_vector_type(4))) float f4v;   // MFMA C/D frag
typedef __attribute__((ext_vector_type(2))) u32 u32x2;

constexpr int B_ = 8, C_ = 256, F_ = 64, T_ = 500, H_ = 512;
constexpr int TT = 30;        // output t-columns per block
constexpr int S_ = 32;        // slots = TT + 2 (halo)
constexpr int NTILE = 17;     // ceil(500/30)

constexpr int HROW = 520;     // u16 / hb row (1040B: 16B-aligned, 4-bank skew)
constexpr int XROW = 264;     // u16 / xs row (528B: 16B-aligned)

// LDS map (37,920 B -> 4 blocks/CU = 32 waves = 100% occupancy):
//   hb  [34][520] u16 @ 0     (rows 2..33 alias as h2b[0..31]; rows 32,33 = GEMM2 N-pad)
//   xs  [32][264] u16 @ 0     (ALIASES hb; dead after P1 MFMA loop barrier)
//   wred[8][32][2] f32 @ 35360  (row-stat partials in P1, col-stat partials in P7a)
//   statm/statr[32]  @ 37408/37536  (GEMM1-row stats, consumed by P4)
//   statm2/statr2[32]@ 37664/37792  (h2-row stats, consumed by P7a epilogue fold)
constexpr int OFF_HB  = 0;
constexpr int OFF_XS  = 0;                       // alias!
constexpr int OFF_WR  = 34 * HROW * 2;           // 35360
constexpr int OFF_SM  = OFF_WR + 2048;           // 37408
constexpr int OFF_SR  = OFF_SM + 128;            // 37536
constexpr int OFF_SM2 = OFF_SR + 128;            // 37664
constexpr int OFF_SR2 = OFF_SM2 + 128;           // 37792
constexpr int SMEM_BYTES = OFF_SR2 + 128;        // 37920

__device__ __forceinline__ u16 f2bf(float f) {
  unsigned u = __float_as_uint(f);
  u += 0x7FFFu + ((u >> 16) & 1u);        // RNE
  return (u16)(u >> 16);
}
__device__ __forceinline__ float bf2f(u16 h) {
  return __uint_as_float(((unsigned)h) << 16);
}

// prep: bf16 weights; fold dw_nw into wpost; A[c]=sum_h postw*nw, cb[c]=sum_h postw*nb + post_b
__global__ __launch_bounds__(512)
void prep_kernel(const float* __restrict__ pw, const float* __restrict__ qw,
                 const float* __restrict__ dnw, const float* __restrict__ dnb,
                 const float* __restrict__ postb,
                 u16* __restrict__ wa, u16* __restrict__ wb,
                 float* __restrict__ Af, float* __restrict__ cbf) {
  __shared__ float red[16];
  int bx = blockIdx.x, tid = threadIdx.x;
  int i = bx * 512 + tid;                 // qw row c=bx, h=tid
  wa[i] = f2bf(pw[i]);
  float q  = qw[i];
  float nw = dnw[tid], nb = dnb[tid];
  float t1 = q * nw, t2 = q * nb;
  wb[i] = f2bf(t1);
#pragma unroll
  for (int mm = 1; mm < 64; mm <<= 1) {
    t1 += __shfl_xor(t1, mm);
    t2 += __shfl_xor(t2, mm);
  }
  if ((tid & 63) == 0) { red[(tid >> 6) * 2] = t1; red[(tid >> 6) * 2 + 1] = t2; }
  __syncthreads();
  if (tid == 0) {
    float a = 0.f, b2 = 0.f;
#pragma unroll
    for (int k = 0; k < 8; k++) { a += red[2 * k]; b2 += red[2 * k + 1]; }
    Af[bx]  = a;
    cbf[bx] = b2 + postb[bx];
  }
}

__global__ __launch_bounds__(512, 8)   // VGPR<=64 so 4 blocks/CU (32 waves) fit
void mixer_kernel(const float* __restrict__ x, const float* __restrict__ state,
                  const float* __restrict__ pre_b, const float* __restrict__ pre_nw,
                  const float* __restrict__ pre_nb,
                  const float* __restrict__ dw_w, const float* __restrict__ dw_b,
                  const float* __restrict__ post_nw, const float* __restrict__ post_nb,
                  const u16* __restrict__ wpre, const u16* __restrict__ wpost,
                  const float* __restrict__ Af, const float* __restrict__ cbf,
                  float* __restrict__ out0, float* __restrict__ out1) {
  extern __shared__ char smem[];
  u16*   hb     = (u16*)  (smem + OFF_HB);   // [34][520]
  u16*   h2b    = hb + 2 * HROW;             // [32][520] = hb rows 2..33
  u16*   xs     = (u16*)  (smem + OFF_XS);   // [32][264] bf16 x tile (aliases hb!)
  float* wred   = (float*)(smem + OFF_WR);   // [8][32][2]
  float* statm  = (float*)(smem + OFF_SM);
  float* statr  = (float*)(smem + OFF_SR);
  float* statm2 = (float*)(smem + OFF_SM2);
  float* statr2 = (float*)(smem + OFF_SR2);

  const int tid  = threadIdx.x;
  const int bx   = blockIdx.x;
  const int tile = bx % NTILE;
  const int f    = (bx / NTILE) % F_;
  const int b    = bx / (NTILE * F_);
  const int t0   = tile * TT;

  const int w    = tid >> 6;        // wave 0..7
  const int lane = tid & 63;
  const int quad = lane >> 4;
  const int l16  = lane & 15;

  // ---- P0: stage x tile as bf16 pairs (slot s -> t = t0-2+s), zero OOB ----
  {
    const float* xp = x + ((size_t)b * C_ * F_ + f) * T_;
    for (int e = tid; e < 128 * S_; e += 512) {     // 4096 c-pairs
      int cpair = e >> 5, s = e & 31;
      int c = cpair * 2;
      int t = t0 - 2 + s;
      float va = 0.f, vb = 0.f;
      if (t >= 0 && t < T_) {
        va = xp[(size_t)c * F_ * T_ + t];
        vb = xp[(size_t)(c + 1) * F_ * T_ + t];
      }
      u32 pk = (u32)f2bf(va) | ((u32)f2bf(vb) << 16);
      *(u32*)(xs + s * XROW + c) = pk;
    }
    // zero hb rows 32,33 == h2b N-pad rows 30,31 (beyond xs alias region)
    hb[32 * HROW + tid] = 0;
    hb[33 * HROW + tid] = 0;
  }
  __syncthreads();

  // ---- P1: GEMM1 FLIPPED: D[o][s] = pre_w * x ; acc rows = channels o.
  //          After alias barrier: writeback relu(+pre_b) -> hb as ds_write_b64,
  //          with per-slot (column) stats partials computed IN-REGISTER (f32). ----
  {
    f4v acc1[2][4];    // [sblk][j]: cols s = sblk*16+l16, rows o = (w+8j)*16+quad*4+r2
#pragma unroll
    for (int sb = 0; sb < 2; sb++)
#pragma unroll
      for (int j = 0; j < 4; j++) acc1[sb][j] = (f4v){0.f, 0.f, 0.f, 0.f};

    const u16* wp[4];
#pragma unroll
    for (int j = 0; j < 4; j++)
      wp[j] = wpre + ((w + 8 * j) * 16 + l16) * C_ + quad * 8;
    const u16* a0p = xs + l16 * XROW + quad * 8;
    const u16* a1p = xs + (16 + l16) * XROW + quad * 8;

#pragma unroll 2
    for (int k = 0; k < 8; k++) {
      int c0 = k * 32;
      s8v xf0 = *(const s8v*)(a0p + c0);
      s8v xf1 = *(const s8v*)(a1p + c0);
#pragma unroll
      for (int j = 0; j < 4; j++) {
        s8v wf = *(const s8v*)(wp[j] + c0);
        acc1[0][j] = __builtin_amdgcn_mfma_f32_16x16x32_bf16(wf, xf0, acc1[0][j], 0, 0, 0);
        acc1[1][j] = __builtin_amdgcn_mfma_f32_16x16x32_bf16(wf, xf1, acc1[1][j], 0, 0, 0);
      }
    }
    __syncthreads();   // all xs reads done before hb writeback overwrites alias region

    float rsum[2] = {0.f, 0.f}, rss[2] = {0.f, 0.f};
#pragma unroll
    for (int j = 0; j < 4; j++) {
      int o0 = (w + 8 * j) * 16 + quad * 4;
      f4v pb4 = *(const f4v*)(pre_b + o0);
#pragma unroll
      for (int sb = 0; sb < 2; sb++) {
        int s = sb * 16 + l16;
        float v0 = fmaxf(acc1[sb][j][0] + pb4[0], 0.f);
        float v1 = fmaxf(acc1[sb][j][1] + pb4[1], 0.f);
        float v2 = fmaxf(acc1[sb][j][2] + pb4[2], 0.f);
        float v3 = fmaxf(acc1[sb][j][3] + pb4[3], 0.f);
        rsum[sb] += (v0 + v1) + (v2 + v3);
        rss[sb]  += v0 * v0 + v1 * v1 + v2 * v2 + v3 * v3;
        u32 lo = (u32)f2bf(v0) | ((u32)f2bf(v1) << 16);
        u32 hi = (u32)f2bf(v2) | ((u32)f2bf(v3) << 16);
        *(u32x2*)(hb + s * HROW + o0) = (u32x2){lo, hi};
      }
    }
#pragma unroll
    for (int sb = 0; sb < 2; sb++) {
      float s_ = rsum[sb], q_ = rss[sb];
      s_ += __shfl_xor(s_, 16); q_ += __shfl_xor(q_, 16);
      s_ += __shfl_xor(s_, 32); q_ += __shfl_xor(q_, 32);
      if (quad == 0) {
        wred[(w * 32 + sb * 16 + l16) * 2 + 0] = s_;
        wred[(w * 32 + sb * 16 + l16) * 2 + 1] = q_;
      }
    }
  }
  __syncthreads();

  // ---- P2: finalize per-slot stats (32 threads, 8 partials each) ----
  if (tid < 32) {
    float sum = 0.f, ss = 0.f;
#pragma unroll
    for (int w8 = 0; w8 < 8; w8++) {
      sum += wred[(w8 * 32 + tid) * 2 + 0];
      ss  += wred[(w8 * 32 + tid) * 2 + 1];
    }
    float mean = sum * (1.f / 512.f);
    float var  = ss * (1.f / 512.f) - mean * mean;
    statm[tid] = mean;
    statr[tid] = rsqrtf(var + 1e-8f);
  }
  __syncthreads();

  // ---- P4: pre-norm (affine from statm/statr) folded into depthwise K=3 + relu,
  //          IN PLACE (h2b = hb+2 rows). out1 emission + tile0 halo from global. ----
  {
    int o = tid;
    float nwp = pre_nw[o], nbp = pre_nb[o];
    float w0 = dw_w[o * 3 + 0], w1 = dw_w[o * 3 + 1], w2 = dw_w[o * 3 + 2];
    float db = dw_b[o];

    if (tile == NTILE - 1) {       // emit new_state = normalized h at t=498,499
      int s0 = T_ - t0;            // slot of t=498
      float a0 = statr[s0] * nwp,     b0 = nbp - statm[s0] * a0;
      float a1 = statr[s0 + 1] * nwp, b1 = nbp - statm[s0 + 1] * a1;
      float* op = out1 + (((size_t)b * H_ + o) * F_ + f) * 2;
      op[0] = bf2f(hb[s0 * HROW + o]) * a0 + b0;
      op[1] = bf2f(hb[(s0 + 1) * HROW + o]) * a1 + b1;
    }

    float v0, v1;
    if (tile == 0) {               // halo = raw state (no norm)
      const float* sp = state + (((size_t)b * H_ + o) * F_ + f) * 2;
      v0 = sp[0]; v1 = sp[1];
    } else {
      float a0 = statr[0] * nwp, b0 = nbp - statm[0] * a0;
      float a1 = statr[1] * nwp, b1 = nbp - statm[1] * a1;
      v0 = bf2f(hb[0 * HROW + o]) * a0 + b0;
      v1 = bf2f(hb[1 * HROW + o]) * a1 + b1;
    }
#pragma unroll 6
    for (int s = 2; s < 32; s++) {
      float a = statr[s] * nwp, bb = nbp - statm[s] * a;
      float v2 = bf2f(hb[s * HROW + o]) * a + bb;   // read before aliased write below
      int t = t0 + s - 2;
      float r = fmaxf(w0 * v0 + w1 * v1 + w2 * v2 + db, 0.f);
      h2b[(s - 2) * HROW + o] = (t < T_) ? f2bf(r) : (u16)0;   // == hb[s*HROW+o]
      v0 = v1; v1 = v2;
    }
  }
  __syncthreads();

  // ---- P5: h2 row STATS ONLY (b64 reads, all 32 rows; pads are zeros -> finite rs).
  //          No normalize pass: the dw-norm is folded into GEMM2's epilogue. ----
  {
    int r = tid >> 4, p = tid & 15;
    const u16* row = h2b + r * HROW;
    float sum = 0.f, ss = 0.f;
#pragma unroll
    for (int i = 0; i < 8; i++) {
      u32x2 d = *(const u32x2*)(row + (p + 16 * i) * 4);
      float a0 = __uint_as_float(d.x << 16);
      float a1 = __uint_as_float(d.x & 0xffff0000u);
      float a2 = __uint_as_float(d.y << 16);
      float a3 = __uint_as_float(d.y & 0xffff0000u);
      sum += (a0 + a1) + (a2 + a3);
      ss  += a0 * a0 + a1 * a1 + a2 * a2 + a3 * a3;
    }
#pragma unroll
    for (int mm = 1; mm < 16; mm <<= 1) {
      sum += __shfl_xor(sum, mm, 16);
      ss  += __shfl_xor(ss,  mm, 16);
    }
    if (p == 0) {
      float mean = sum * (1.f / 512.f);
      float var  = ss * (1.f / 512.f) - mean * mean;
      statm2[r] = mean;
      statr2[r] = rsqrtf(var + 1e-8f);
    }
  }
  // NO barrier: P6 below only reads h2b (written before bar5); statm2 read after bar6.

  // ---- P6: GEMM2  D[c][s2] = wpost' * h2_raw (acc in registers) ----
  f4v acc[2][2];
  {
#pragma unroll
    for (int mi = 0; mi < 2; mi++)
#pragma unroll
      for (int ni = 0; ni < 2; ni++) acc[mi][ni] = (f4v){0.f, 0.f, 0.f, 0.f};

    const u16* ap0 = wpost + ((2 * w + 0) * 16 + l16) * H_ + quad * 8;
    const u16* ap1 = wpost + ((2 * w + 1) * 16 + l16) * H_ + quad * 8;
    const u16* bp0 = h2b + (0 + l16) * HROW + quad * 8;
    const u16* bp1 = h2b + (16 + l16) * HROW + quad * 8;

#pragma unroll 4
    for (int k = 0; k < 16; k++) {
      int ko = k * 32;
      s8v a0 = *(const s8v*)(ap0 + ko);
      s8v a1 = *(const s8v*)(ap1 + ko);
      s8v b0 = *(const s8v*)(bp0 + ko);
      s8v b1 = *(const s8v*)(bp1 + ko);
      acc[0][0] = __builtin_amdgcn_mfma_f32_16x16x32_bf16(a0, b0, acc[0][0], 0, 0, 0);
      acc[0][1] = __builtin_amdgcn_mfma_f32_16x16x32_bf16(a0, b1, acc[0][1], 0, 0, 0);
      acc[1][0] = __builtin_amdgcn_mfma_f32_16x16x32_bf16(a1, b0, acc[1][0], 0, 0, 0);
      acc[1][1] = __builtin_amdgcn_mfma_f32_16x16x32_bf16(a1, b1, acc[1][1], 0, 0, 0);
    }
  }
  __syncthreads();   // bar6: statm2/statr2 visible

  // ---- P7a: apply dw-norm fold in registers: v = rs2*(G - m2*A[c]) + cb[c];
  //           then per-column stats partials -> wred ----
  {
    float m20 = statm2[l16],      r20 = statr2[l16];
    float m21 = statm2[16 + l16], r21 = statr2[16 + l16];
    float rm0 = r20 * m20, rm1 = r21 * m21;
    f4v A0 = *(const f4v*)(Af  + (2 * w + 0) * 16 + quad * 4);
    f4v A1 = *(const f4v*)(Af  + (2 * w + 1) * 16 + quad * 4);
    f4v c0 = *(const f4v*)(cbf + (2 * w + 0) * 16 + quad * 4);
    f4v c1 = *(const f4v*)(cbf + (2 * w + 1) * 16 + quad * 4);

    float psum0 = 0.f, pss0 = 0.f, psum1 = 0.f, pss1 = 0.f;
#pragma unroll
    for (int mi = 0; mi < 2; mi++)
#pragma unroll
      for (int r2 = 0; r2 < 4; r2++) {
        float a_ = mi ? A1[r2] : A0[r2];
        float cc = mi ? c1[r2] : c0[r2];
        float t0_ = fmaf(-rm0, a_, cc);
        float t1_ = fmaf(-rm1, a_, cc);
        float v0 = fmaf(r20, acc[mi][0][r2], t0_);
        float v1 = fmaf(r21, acc[mi][1][r2], t1_);
        acc[mi][0][r2] = v0;               // overwrite acc with folded v
        acc[mi][1][r2] = v1;
        psum0 += v0; pss0 += v0 * v0;
        psum1 += v1; pss1 += v1 * v1;
      }
    psum0 += __shfl_xor(psum0, 16); pss0 += __shfl_xor(pss0, 16);
    psum1 += __shfl_xor(psum1, 16); pss1 += __shfl_xor(pss1, 16);
    psum0 += __shfl_xor(psum0, 32); pss0 += __shfl_xor(pss0, 32);
    psum1 += __shfl_xor(psum1, 32); pss1 += __shfl_xor(pss1, 32);
    if (quad == 0) {
      wred[(w * 32 + l16)      * 2 + 0] = psum0;
      wred[(w * 32 + l16)      * 2 + 1] = pss0;
      wred[(w * 32 + 16 + l16) * 2 + 0] = psum1;
      wred[(w * 32 + 16 + l16) * 2 + 1] = pss1;
    }
  }
  __syncthreads();

  // ---- P8: per-lane col-stat finalize (broadcast reads) + norm + residual + store ----
  {
    float sum0 = 0.f, ss0 = 0.f, sum1 = 0.f, ss1 = 0.f;
#pragma unroll
    for (int w8 = 0; w8 < 8; w8++) {
      sum0 += wred[(w8 * 32 + l16) * 2 + 0];
      ss0  += wred[(w8 * 32 + l16) * 2 + 1];
      sum1 += wred[(w8 * 32 + 16 + l16) * 2 + 0];
      ss1  += wred[(w8 * 32 + 16 + l16) * 2 + 1];
    }
    float m0 = sum0 * (1.f / 256.f);
    float rs0 = rsqrtf(ss0 * (1.f / 256.f) - m0 * m0 + 1e-8f);
    float m1 = sum1 * (1.f / 256.f);
    float rs1 = rsqrtf(ss1 * (1.f / 256.f) - m1 * m1 + 1e-8f);

    int s20 = l16, s21 = 16 + l16;
    bool ok0 = (t0 + s20) < T_;
    bool ok1 = (s21 < TT) && ((t0 + s21) < T_);
#pragma unroll
    for (int mi = 0; mi < 2; mi++) {
      int c0i = (2 * w + mi) * 16 + quad * 4;
      f4v nw4 = *(const f4v*)(post_nw + c0i);
      f4v nb4 = *(const f4v*)(post_nb + c0i);
#pragma unroll
      for (int r2 = 0; r2 < 4; r2++) {
        int c = c0i + r2;
        size_t base = (((size_t)b * C_ + c) * F_ + f) * (size_t)T_;
        if (ok0) {
          size_t idx = base + t0 + s20;
          out0[idx] = (acc[mi][0][r2] - m0) * rs0 * nw4[r2] + nb4[r2] + x[idx];
        }
        if (ok1) {
          size_t idx = base + t0 + s21;
          out0[idx] = (acc[mi][1][r2] - m1) * rs1 * nw4[r2] + nb4[r2] + x[idx];
        }
      }
    }
  }
}

extern "C" void kernel_launch(void* const* d_in, const int* in_sizes, int n_in,
                              void* d_out, int out_size, void* d_ws, size_t ws_size,
                              hipStream_t stream) {
  const float* x       = (const float*)d_in[0];
  const float* state   = (const float*)d_in[1];
  const float* pre_w   = (const float*)d_in[2];
  const float* pre_b   = (const float*)d_in[3];
  const float* pre_nw  = (const float*)d_in[4];
  const float* pre_nb  = (const float*)d_in[5];
  const float* dw_w    = (const float*)d_in[6];
  const float* dw_b    = (const float*)d_in[7];
  const float* dw_nw   = (const float*)d_in[8];
  const float* dw_nb   = (const float*)d_in[9];
  const float* post_w  = (const float*)d_in[10];
  const float* post_b  = (const float*)d_in[11];
  const float* post_nw = (const float*)d_in[12];
  const float* post_nb = (const float*)d_in[13];

  float* out0 = (float*)d_out;
  float* out1 = out0 + (size_t)B_ * C_ * F_ * T_;

  u16*   wpre  = (u16*)d_ws;                       // 256KB
  u16*   wpost = wpre + H_ * C_;                   // 256KB
  float* Abuf  = (float*)((char*)d_ws + 2 * H_ * C_ * sizeof(u16));   // 1KB
  float* cbuf  = Abuf + C_;                                           // 1KB

  prep_kernel<<<dim3((H_ * C_) / 512), dim3(512), 0, stream>>>(
      pre_w, post_w, dw_nw, dw_nb, post_b, wpre, wpost, Abuf, cbuf);
  mixer_kernel<<<dim3(B_ * F_ * NTILE), dim3(512), SMEM_BYTES, stream>>>(
      x, state, pre_b, pre_nw, pre_nb, dw_w, dw_b,
      post_nw, post_nb, wpre, wpost, Abuf, cbuf, out0, out1);
}